// Round 1
// baseline (183.797 us; speedup 1.0000x reference)
//
#include <hip/hip_runtime.h>

// CGM: channel-group max filter.
// x: [B=32, C=256, W=56, H=56] fp32, groups of g=4 along C.
// out[b,c,w,h] = x if (x == max over its group) && (x > 0), clamped to max_clamp; else 0.
//
// Memory-bound: 102.8 MB in + 102.8 MB out. Each thread handles 4 consecutive
// spatial positions (float4) across all 4 channels of one group:
// 4x float4 loads (each coalesced; channels are W*H=3136 floats apart),
// elementwise max, predicated writes.

#define SPATIAL 3136      // 56*56
#define SPATIAL4 784      // SPATIAL/4
#define GROUPS_TOTAL (32 * 64)  // B * (C/group_size)

__global__ __launch_bounds__(256) void CGM_16707422781821_kernel(
    const float* __restrict__ x,
    float* __restrict__ out,
    const float* __restrict__ max_clamp_p) {
    const int t = blockIdx.x * blockDim.x + threadIdx.x;
    // t in [0, GROUPS_TOTAL * SPATIAL4); exact grid, no bounds check.
    const int plane = t / SPATIAL4;   // which (b, group)
    const int pos4  = t - plane * SPATIAL4;

    const float clampv = *max_clamp_p;

    // base element offset of channel 0 of this group at this spatial chunk
    const long base = (long)plane * (4L * SPATIAL) + (long)pos4 * 4;

    const float4* p0 = (const float4*)(x + base);
    const float4* p1 = (const float4*)(x + base + SPATIAL);
    const float4* p2 = (const float4*)(x + base + 2 * SPATIAL);
    const float4* p3 = (const float4*)(x + base + 3 * SPATIAL);

    float4 v0 = *p0;
    float4 v1 = *p1;
    float4 v2 = *p2;
    float4 v3 = *p3;

    // elementwise group max across the 4 channels
    float4 m;
    m.x = fmaxf(fmaxf(v0.x, v1.x), fmaxf(v2.x, v3.x));
    m.y = fmaxf(fmaxf(v0.y, v1.y), fmaxf(v2.y, v3.y));
    m.z = fmaxf(fmaxf(v0.z, v1.z), fmaxf(v2.z, v3.z));
    m.w = fmaxf(fmaxf(v0.w, v1.w), fmaxf(v2.w, v3.w));

#define FILT(v, mm) (((v) == (mm) && (v) > 0.0f) ? fminf((v), clampv) : 0.0f)
    float4 o0, o1, o2, o3;
    o0.x = FILT(v0.x, m.x); o0.y = FILT(v0.y, m.y); o0.z = FILT(v0.z, m.z); o0.w = FILT(v0.w, m.w);
    o1.x = FILT(v1.x, m.x); o1.y = FILT(v1.y, m.y); o1.z = FILT(v1.z, m.z); o1.w = FILT(v1.w, m.w);
    o2.x = FILT(v2.x, m.x); o2.y = FILT(v2.y, m.y); o2.z = FILT(v2.z, m.z); o2.w = FILT(v2.w, m.w);
    o3.x = FILT(v3.x, m.x); o3.y = FILT(v3.y, m.y); o3.z = FILT(v3.z, m.z); o3.w = FILT(v3.w, m.w);
#undef FILT

    float4* q0 = (float4*)(out + base);
    float4* q1 = (float4*)(out + base + SPATIAL);
    float4* q2 = (float4*)(out + base + 2 * SPATIAL);
    float4* q3 = (float4*)(out + base + 3 * SPATIAL);
    *q0 = o0;
    *q1 = o1;
    *q2 = o2;
    *q3 = o3;
}

extern "C" void kernel_launch(void* const* d_in, const int* in_sizes, int n_in,
                              void* d_out, int out_size, void* d_ws, size_t ws_size,
                              hipStream_t stream) {
    const float* x = (const float*)d_in[0];
    // d_in[1] = group_size (int, ==4, structural — hardcoded)
    const float* max_clamp_p = (const float*)d_in[2];
    float* out = (float*)d_out;

    const int total_threads = GROUPS_TOTAL * SPATIAL4;  // 1,605,632
    const int block = 256;
    const int grid = total_threads / block;             // 6272, exact
    CGM_16707422781821_kernel<<<grid, block, 0, stream>>>(x, out, max_clamp_p);
}

// Round 2
// 173.488 us; speedup vs baseline: 1.0594x; 1.0594x over previous
//
#include <hip/hip_runtime.h>

// CGM: channel-group max filter.
// x: [B=32, C=256, W=56, H=56] fp32, groups of g=4 along C.
// out[b,c,w,h] = x if (x == max over its group) && (x > 0), clamped to max_clamp; else 0.
//
// Memory-bound streaming: 102.8 MB in + 102.8 MB out, zero reuse.
// Each thread handles 4 consecutive spatial positions (float4) across all 4
// channels of one group. Non-temporal load/store hints (nt bit) keep the
// streaming traffic from thrashing L2/LLC.

#define SPATIAL 3136      // 56*56
#define SPATIAL4 784      // SPATIAL/4
#define GROUPS_TOTAL (32 * 64)  // B * (C/group_size)

typedef float v4f __attribute__((ext_vector_type(4)));

__global__ __launch_bounds__(256) void CGM_16707422781821_kernel(
    const float* __restrict__ x,
    float* __restrict__ out,
    const float* __restrict__ max_clamp_p) {
    const int t = blockIdx.x * blockDim.x + threadIdx.x;
    // t in [0, GROUPS_TOTAL * SPATIAL4); exact grid, no bounds check.
    const int plane = t / SPATIAL4;   // which (b, group)
    const int pos4  = t - plane * SPATIAL4;

    const float clampv = *max_clamp_p;

    // base element offset of channel 0 of this group at this spatial chunk
    const long base = (long)plane * (4L * SPATIAL) + (long)pos4 * 4;

    const v4f v0 = __builtin_nontemporal_load((const v4f*)(x + base));
    const v4f v1 = __builtin_nontemporal_load((const v4f*)(x + base + SPATIAL));
    const v4f v2 = __builtin_nontemporal_load((const v4f*)(x + base + 2 * SPATIAL));
    const v4f v3 = __builtin_nontemporal_load((const v4f*)(x + base + 3 * SPATIAL));

    // elementwise group max across the 4 channels
    v4f m;
    m.x = fmaxf(fmaxf(v0.x, v1.x), fmaxf(v2.x, v3.x));
    m.y = fmaxf(fmaxf(v0.y, v1.y), fmaxf(v2.y, v3.y));
    m.z = fmaxf(fmaxf(v0.z, v1.z), fmaxf(v2.z, v3.z));
    m.w = fmaxf(fmaxf(v0.w, v1.w), fmaxf(v2.w, v3.w));

#define FILT(v, mm) (((v) == (mm) && (v) > 0.0f) ? fminf((v), clampv) : 0.0f)
    v4f o0, o1, o2, o3;
    o0.x = FILT(v0.x, m.x); o0.y = FILT(v0.y, m.y); o0.z = FILT(v0.z, m.z); o0.w = FILT(v0.w, m.w);
    o1.x = FILT(v1.x, m.x); o1.y = FILT(v1.y, m.y); o1.z = FILT(v1.z, m.z); o1.w = FILT(v1.w, m.w);
    o2.x = FILT(v2.x, m.x); o2.y = FILT(v2.y, m.y); o2.z = FILT(v2.z, m.z); o2.w = FILT(v2.w, m.w);
    o3.x = FILT(v3.x, m.x); o3.y = FILT(v3.y, m.y); o3.z = FILT(v3.z, m.z); o3.w = FILT(v3.w, m.w);
#undef FILT

    __builtin_nontemporal_store(o0, (v4f*)(out + base));
    __builtin_nontemporal_store(o1, (v4f*)(out + base + SPATIAL));
    __builtin_nontemporal_store(o2, (v4f*)(out + base + 2 * SPATIAL));
    __builtin_nontemporal_store(o3, (v4f*)(out + base + 3 * SPATIAL));
}

extern "C" void kernel_launch(void* const* d_in, const int* in_sizes, int n_in,
                              void* d_out, int out_size, void* d_ws, size_t ws_size,
                              hipStream_t stream) {
    const float* x = (const float*)d_in[0];
    // d_in[1] = group_size (int, ==4, structural — hardcoded)
    const float* max_clamp_p = (const float*)d_in[2];
    float* out = (float*)d_out;

    const int total_threads = GROUPS_TOTAL * SPATIAL4;  // 1,605,632
    const int block = 256;
    const int grid = total_threads / block;             // 6272, exact
    CGM_16707422781821_kernel<<<grid, block, 0, stream>>>(x, out, max_clamp_p);
}